// Round 1
// baseline (89.617 us; speedup 1.0000x reference)
//
#include <hip/hip_runtime.h>

#define BQ 64
#define LQ 32
#define BD 128
#define LD 192
#define TOK_D 32
#define CLS_D 768

// One block per (q, d) output element. 8192 blocks x 256 threads.
// Exploits id-match sparsity: the 32-dim token dot is only computed when
// query_id == doc_id (~1/5000 of pairs); non-matches contribute exactly 0
// to the max, matching jnp.where(match, scores, 0).max(axis=-1).
__global__ __launch_bounds__(256) void coil_kernel(
    const float* __restrict__ qtok,   // [BQ, LQ, TOK_D]
    const float* __restrict__ dtok,   // [BD, LD, TOK_D]
    const float* __restrict__ qcls,   // [BQ, CLS_D]
    const float* __restrict__ dcls,   // [BD, CLS_D]
    const int*   __restrict__ qids,   // [BQ, LQ]
    const int*   __restrict__ dids,   // [BD, LD]
    const int*   __restrict__ qatt,   // [BQ, LQ]
    float*       __restrict__ out)    // [BQ, BD]
{
    const int blk = blockIdx.x;
    const int q = blk >> 7;          // / BD (=128)
    const int d = blk & (BD - 1);
    const int t = threadIdx.x;

    __shared__ int   s_qid[LQ];
    __shared__ int   s_att[LQ];
    __shared__ int   s_did[LD];
    __shared__ float s_tok[LQ];
    __shared__ float s_red[4];

    if (t < LQ) {
        s_qid[t] = qids[q * LQ + t];
        s_att[t] = qatt[q * LQ + t];
    }
    if (t < LD) {
        s_did[t] = dids[d * LD + t];
    }
    __syncthreads();

    // --- token max-sim: 8 threads per query position i, each scans 24 doc j's
    const int i = t >> 3;            // 0..31
    const int k = t & 7;             // 0..7
    const float* qrow = qtok + (q * LQ + i) * TOK_D;
    const int myqid = s_qid[i];
    float lmax = -INFINITY;
    for (int j = k; j < LD; j += 8) {
        float val = 0.0f;
        if (s_did[j] == myqid) {
            const float* drow = dtok + (d * LD + j) * TOK_D;
            float acc = 0.0f;
            #pragma unroll
            for (int e = 0; e < TOK_D; ++e) acc = fmaf(qrow[e], drow[e], acc);
            val = acc;
        }
        lmax = fmaxf(lmax, val);
    }
    // reduce max across the 8-lane group (lanes i*8 .. i*8+7, contiguous in wave)
    lmax = fmaxf(lmax, __shfl_xor(lmax, 1));
    lmax = fmaxf(lmax, __shfl_xor(lmax, 2));
    lmax = fmaxf(lmax, __shfl_xor(lmax, 4));
    if (k == 0) s_tok[i] = lmax;

    // --- CLS dot: 768 dims across 256 threads
    float part = 0.0f;
    {
        const float* qc = qcls + q * CLS_D;
        const float* dc = dcls + d * CLS_D;
        for (int c = t; c < CLS_D; c += 256) part = fmaf(qc[c], dc[c], part);
    }
    #pragma unroll
    for (int off = 32; off >= 1; off >>= 1) part += __shfl_xor(part, off);
    if ((t & 63) == 0) s_red[t >> 6] = part;
    __syncthreads();

    if (t == 0) {
        // qmask: attention mask with sep position (sum-1) zeroed
        int msum = 0;
        #pragma unroll
        for (int ii = 0; ii < LQ; ++ii) msum += s_att[ii];
        const int sep = msum - 1;
        float tsum = 0.0f;
        for (int ii = 1; ii < LQ; ++ii) {   // drop CLS position (i=0)
            const float m = (ii == sep) ? 0.0f : (float)s_att[ii];
            tsum += s_tok[ii] * m;
        }
        const float cls = s_red[0] + s_red[1] + s_red[2] + s_red[3];
        out[q * BD + d] = tsum + cls;
    }
}

extern "C" void kernel_launch(void* const* d_in, const int* in_sizes, int n_in,
                              void* d_out, int out_size, void* d_ws, size_t ws_size,
                              hipStream_t stream) {
    const float* qtok = (const float*)d_in[0];
    const float* dtok = (const float*)d_in[1];
    const float* qcls = (const float*)d_in[2];
    const float* dcls = (const float*)d_in[3];
    const int*   qids = (const int*)d_in[4];
    const int*   dids = (const int*)d_in[5];
    const int*   qatt = (const int*)d_in[6];
    float* out = (float*)d_out;

    coil_kernel<<<BQ * BD, 256, 0, stream>>>(qtok, dtok, qcls, dcls,
                                             qids, dids, qatt, out);
}

// Round 2
// 81.300 us; speedup vs baseline: 1.1023x; 1.1023x over previous
//
#include <hip/hip_runtime.h>

#define BQ 64
#define LQ 32
#define BD 128
#define LD 192
#define TOK_D 32
#define CLS_D 768

// One wave (64 threads) per (q,d) output element: 8192 blocks = 8 waves/SIMD,
// exactly one occupancy round on 256 CUs. Exploits id-match sparsity: the
// 32-dim dot is only computed when query_id == doc_id (~1/5000 of pairs).
// Non-matches contribute exactly 0 to the max (tracked via hadZero so the
// pathological all-match case keeps reference semantics).
__global__ __launch_bounds__(64) void coil_kernel(
    const float* __restrict__ qtok,   // [BQ, LQ, TOK_D]
    const float* __restrict__ dtok,   // [BD, LD, TOK_D]
    const float* __restrict__ qcls,   // [BQ, CLS_D]
    const float* __restrict__ dcls,   // [BD, CLS_D]
    const int*   __restrict__ qids,   // [BQ, LQ]
    const int*   __restrict__ dids,   // [BD, LD]
    const int*   __restrict__ qatt,   // [BQ, LQ]
    float*       __restrict__ out)    // [BQ, BD]
{
    const int blk = blockIdx.x;
    const int q = blk >> 7;          // / BD
    const int d = blk & (BD - 1);
    const int t = threadIdx.x;       // 0..63

    __shared__ int   s_did[LD];      // 192 ints
    __shared__ int   s_qid[LQ];
    __shared__ int   s_att[LQ];
    __shared__ float s_tok[LQ];

    // --- vectorized staging: 48 int4 (doc ids) + 8 int4 (q ids) + 8 int4 (att)
    if (t < 48) {
        ((int4*)s_did)[t] = ((const int4*)(dids + d * LD))[t];
    } else if (t < 56) {
        ((int4*)s_qid)[t - 48] = ((const int4*)(qids + q * LQ))[t - 48];
    } else {
        ((int4*)s_att)[t - 56] = ((const int4*)(qatt + q * LQ))[t - 56];
    }
    __syncthreads();   // single wave: compiles to waitcnt + cheap barrier

    // --- token max-sim: 2 lanes per query token i; each lane scans 24 id-quads
    const int i = t >> 1;            // 0..31
    const int k = t & 1;             // 0..1
    const int myqid = s_qid[i];
    const float4* qr = (const float4*)(qtok + (q * LQ + i) * TOK_D);

    float lmax = -INFINITY;
    bool hadZero = false;

    auto dotj = [&](int j) -> float {
        const float4* dr = (const float4*)(dtok + (d * LD + j) * TOK_D);
        float acc = 0.0f;
        #pragma unroll
        for (int e = 0; e < TOK_D / 4; ++e) {
            float4 a = qr[e], b = dr[e];
            acc = fmaf(a.x, b.x, acc);
            acc = fmaf(a.y, b.y, acc);
            acc = fmaf(a.z, b.z, acc);
            acc = fmaf(a.w, b.w, acc);
        }
        return acc;
    };

    for (int c = k; c < LD / 4; c += 2) {        // 24 quads per lane
        const int4 ids = ((const int4*)s_did)[c]; // ds_read_b128
        const int j0 = c * 4;
        if (ids.x == myqid) lmax = fmaxf(lmax, dotj(j0 + 0)); else hadZero = true;
        if (ids.y == myqid) lmax = fmaxf(lmax, dotj(j0 + 1)); else hadZero = true;
        if (ids.z == myqid) lmax = fmaxf(lmax, dotj(j0 + 2)); else hadZero = true;
        if (ids.w == myqid) lmax = fmaxf(lmax, dotj(j0 + 3)); else hadZero = true;
    }
    if (hadZero) lmax = fmaxf(lmax, 0.0f);
    lmax = fmaxf(lmax, __shfl_xor(lmax, 1));     // merge the 2 lanes of token i
    if (k == 0) s_tok[i] = lmax;

    // --- CLS dot: 768 dims = 192 float4, 3 per lane
    float part = 0.0f;
    {
        const float4* qc = (const float4*)(qcls + q * CLS_D);
        const float4* dc = (const float4*)(dcls + d * CLS_D);
        #pragma unroll
        for (int r = 0; r < 3; ++r) {
            float4 a = qc[t + 64 * r];
            float4 b = dc[t + 64 * r];
            part = fmaf(a.x, b.x, part);
            part = fmaf(a.y, b.y, part);
            part = fmaf(a.z, b.z, part);
            part = fmaf(a.w, b.w, part);
        }
    }
    __syncthreads();

    // --- masked token sum + cls, parallel reduce
    const int att = s_att[t & 31];
    int msum = att;                              // sum of attention mask
    msum += __shfl_xor(msum, 1);
    msum += __shfl_xor(msum, 2);
    msum += __shfl_xor(msum, 4);
    msum += __shfl_xor(msum, 8);
    msum += __shfl_xor(msum, 16);
    const int sep = msum - 1;                    // [SEP] position to zero

    float tot = part;
    if (t >= 1 && t < LQ) {                      // drop CLS position (i=0)
        const float m = (t == sep) ? 0.0f : (float)att;
        tot += s_tok[t] * m;
    }
    #pragma unroll
    for (int off = 1; off < 64; off <<= 1) tot += __shfl_xor(tot, off);
    if (t == 0) out[q * BD + d] = tot;
}

extern "C" void kernel_launch(void* const* d_in, const int* in_sizes, int n_in,
                              void* d_out, int out_size, void* d_ws, size_t ws_size,
                              hipStream_t stream) {
    const float* qtok = (const float*)d_in[0];
    const float* dtok = (const float*)d_in[1];
    const float* qcls = (const float*)d_in[2];
    const float* dcls = (const float*)d_in[3];
    const int*   qids = (const int*)d_in[4];
    const int*   dids = (const int*)d_in[5];
    const int*   qatt = (const int*)d_in[6];
    float* out = (float*)d_out;

    coil_kernel<<<BQ * BD, 64, 0, stream>>>(qtok, dtok, qcls, dcls,
                                            qids, dids, qatt, out);
}